// Round 2
// baseline (3031.051 us; speedup 1.0000x reference)
//
#include <hip/hip_runtime.h>

#define HH 512
#define WW 512
#define SS (HH * WW)          // 262144 elements per plane
#define P16N (16 * SS)        // one input's batch of gray planes

// ---------------- grad (gray fused) ----------------

__device__ __forceinline__ float grayAt(const float* __restrict__ rgb, size_t imgBase, int pix) {
    return 0.299f * rgb[imgBase + pix]
         + 0.587f * rgb[imgBase + SS + pix]
         + 0.114f * rgb[imgBase + 2 * SS + pix];
}

// dir 0 = x (cols), 1 = y (rows). Forward diff, neighbor beyond edge = 0 pad.
__global__ void grad_kernel(const float* __restrict__ rgb, float* __restrict__ dst, int dir) {
    int idx = blockIdx.x * 256 + threadIdx.x;           // [0, P16N)
    int img = idx >> 18;                                // SS = 2^18
    int pix = idx & (SS - 1);
    int i = pix >> 9, j = pix & (WW - 1);
    size_t imgBase = (size_t)img * 3 * SS;
    float a = grayAt(rgb, imgBase, pix);
    float b = 0.f;
    if (dir == 0) { if (j < WW - 1) b = grayAt(rgb, imgBase, pix + 1); }
    else          { if (i < HH - 1) b = grayAt(rgb, imgBase, pix + WW); }
    dst[idx] = a - b;
}

// ---------------- fused separable pool (row+col in one kernel) ----------------
// OP: 0=max, 1=min, 2=avg (sum/count). Valid-only windows (matches -inf / zero-pad).
// EPI: 0=none, 1=gn1 (v=gmin1; e1=g, e2=gmax1), 2=final map (v=pmin; e1=go, e2=pmax, e3=gn1),
//      3=abs output.
template <int OP, bool PREABS, int R, int EPI>
__global__ __launch_bounds__(256) void fused_pool(
    const float* __restrict__ src, float* __restrict__ dst,
    const float* __restrict__ e1, const float* __restrict__ e2,
    const float* __restrict__ e3)
{
    constexpr int TH    = (R == 8) ? 8 : 16;     // output rows per block (LDS-limited)
    constexpr int ROWS  = TH + 2 * R;            // rows of row-pooled halo tile
    constexpr int SHIFT = (R == 8) ? 6 : 5;      // log2(512/TH)
    __shared__ float rp[ROWS][WW + 1];           // +1 pad: stride 513 rotates banks

    const int plane = blockIdx.x >> SHIFT;
    const int tile  = blockIdx.x & ((1 << SHIFT) - 1);
    const int i0    = tile * TH;                 // first output row
    const size_t pbase = (size_t)plane * SS;
    const float* sp = src + pbase;
    const int tid = threadIdx.x;

    // ---- Stage A: row pooling into LDS for rows [i0-R, i0+TH-1+R] (clamped) ----
    if (OP == 2) {
        // sliding-window sum: thread owns (row rr, 64-col segment seg)
        int rr = tid & 31, seg = tid >> 5;       // rr in [0,32), seg in [0,8)
        if (rr < ROWS) {
            int gi = i0 - R + rr;
            if ((unsigned)gi < (unsigned)HH) {
                const float* rowp = sp + (size_t)gi * WW;
                int j0 = seg << 6;
                float acc = 0.f;
                int lo = j0 - R; if (lo < 0) lo = 0;
                for (int jj = lo; jj <= j0 + R; ++jj) {      // j0+R <= 456 < 512
                    float v = rowp[jj]; if (PREABS) v = fabsf(v); acc += v;
                }
                rp[rr][j0] = acc;
                for (int d = 1; d < 64; ++d) {
                    int j = j0 + d;
                    int add = j + R, sub = j - R - 1;
                    if (add < WW)  { float v = rowp[add]; if (PREABS) v = fabsf(v); acc += v; }
                    if (sub >= 0)  { float v = rowp[sub]; if (PREABS) v = fabsf(v); acc -= v; }
                    rp[rr][j] = acc;
                }
            }
        }
    } else {
        // brute-force max/min (window <= 9 taps), global reads served by L1
        for (int idx = tid; idx < ROWS * WW; idx += 256) {
            int rr = idx >> 9, j = idx & (WW - 1);
            int gi = i0 - R + rr;
            if ((unsigned)gi >= (unsigned)HH) continue;
            const float* rowp = sp + (size_t)gi * WW;
            int lo = j - R; if (lo < 0) lo = 0;
            int hi = j + R; if (hi > WW - 1) hi = WW - 1;
            float acc = (OP == 0) ? -3.402823466e38f : 3.402823466e38f;
            for (int jj = lo; jj <= hi; ++jj) {
                float v = rowp[jj]; if (PREABS) v = fabsf(v);
                acc = (OP == 0) ? fmaxf(acc, v) : fminf(acc, v);
            }
            rp[rr][j] = acc;
        }
    }
    __syncthreads();

    // ---- Stage B: column pooling from LDS, TH x 512 outputs ----
    if (OP == 2) {
        for (int j = tid; j < WW; j += 256) {    // 2 columns per thread
            int cw = min(j + R, WW - 1) - max(j - R, 0) + 1;
            float acc = 0.f;
            int glo = max(i0 - R, 0), ghi = min(i0 + R, HH - 1);
            for (int gi = glo; gi <= ghi; ++gi) acc += rp[gi - (i0 - R)][j];
            for (int oi = 0; oi < TH; ++oi) {
                int i = i0 + oi;
                if (oi > 0) {
                    int add = i + R, sub = i - R - 1;
                    if (add < HH) acc += rp[add - (i0 - R)][j];
                    if (sub >= 0) acc -= rp[sub - (i0 - R)][j];
                }
                int ch = min(i + R, HH - 1) - max(i - R, 0) + 1;
                float v = acc / (float)(ch * cw);
                size_t o = pbase + (size_t)i * WW + j;
                if (EPI == 1) {
                    float ga = fabsf(e1[o]);
                    v = (ga - v) / (fabsf(e2[o] - v) + 1e-4f);
                } else if (EPI == 2) {
                    float gn = (e1[o] - v) / (fabsf(e2[o] - v) + 1e-4f);
                    v = (gn + 0.01f) * e3[o];
                } else if (EPI == 3) {
                    v = fabsf(v);
                }
                dst[o] = v;
            }
        }
    } else {
        for (int idx = tid; idx < TH * WW; idx += 256) {
            int oi = idx >> 9, j = idx & (WW - 1);
            int i = i0 + oi;
            int glo = max(i - R, 0), ghi = min(i + R, HH - 1);
            float acc = (OP == 0) ? -3.402823466e38f : 3.402823466e38f;
            for (int gi = glo; gi <= ghi; ++gi) {
                float v = rp[gi - (i0 - R)][j];
                acc = (OP == 0) ? fmaxf(acc, v) : fminf(acc, v);
            }
            dst[pbase + (size_t)i * WW + j] = acc;
        }
    }
}

// ---------------- reduction (two-stage, no hot atomics) ----------------

__global__ __launch_bounds__(256) void reduce1(const float* __restrict__ mR,
                                               const float* __restrict__ mL,
                                               float* __restrict__ partials) {
    int tid = blockIdx.x * 256 + threadIdx.x;
    float v = 0.f;
    for (int i = tid; i < P16N; i += 256 * 1024) {
        float a = mR[i], b = mL[i];
        v += a * expf(-10.f * a) * expf(-10.f * b);
    }
    for (int off = 32; off; off >>= 1) v += __shfl_down(v, off);
    __shared__ float lds[4];
    int lane = threadIdx.x & 63, wv = threadIdx.x >> 6;
    if (lane == 0) lds[wv] = v;
    __syncthreads();
    if (threadIdx.x == 0) partials[blockIdx.x] = lds[0] + lds[1] + lds[2] + lds[3];
}

__global__ __launch_bounds__(256) void reduce2(const float* __restrict__ partials,
                                               float* __restrict__ out, float scale, int n) {
    float v = 0.f;
    for (int i = threadIdx.x; i < n; i += 256) v += partials[i];
    for (int off = 32; off; off >>= 1) v += __shfl_down(v, off);
    __shared__ float lds[4];
    int lane = threadIdx.x & 63, wv = threadIdx.x >> 6;
    if (lane == 0) lds[wv] = v;
    __syncthreads();
    if (threadIdx.x == 0) atomicAdd(out, (lds[0] + lds[1] + lds[2] + lds[3]) * scale);
}

// ---------------- host orchestration ----------------

static inline int nblk(int total) { return (total + 255) / 256; }

// G holds g on entry; final per-pixel map written to `map`. planes = stacked plane count.
static void pipeline(float* G, float* A, float* B, float* C, float* D, float* map,
                     int planes, hipStream_t s) {
    int g32 = planes * 32;   // pools with TH=16
    int g64 = planes * 64;   // pools with TH=8 (R=8)
    fused_pool<0, true , 4, 0><<<g32, 256, 0, s>>>(G, A, nullptr, nullptr, nullptr); // pmax1=max9|g|
    fused_pool<1, true , 4, 0><<<g32, 256, 0, s>>>(G, B, nullptr, nullptr, nullptr); // pmin1=min9|g|
    fused_pool<2, false, 8, 0><<<g64, 256, 0, s>>>(A, C, nullptr, nullptr, nullptr); // gmax1=avg17
    fused_pool<2, false, 8, 1><<<g64, 256, 0, s>>>(B, D, G, C, nullptr);             // gn1
    fused_pool<2, false, 2, 3><<<g32, 256, 0, s>>>(G, A, nullptr, nullptr, nullptr); // go=|avg5 g|
    fused_pool<0, false, 3, 0><<<g32, 256, 0, s>>>(A, B, nullptr, nullptr, nullptr); // max7(go)
    fused_pool<2, false, 3, 0><<<g32, 256, 0, s>>>(B, C, nullptr, nullptr, nullptr); // pmax=avg7
    fused_pool<1, false, 3, 0><<<g32, 256, 0, s>>>(A, B, nullptr, nullptr, nullptr); // min7(go)
    fused_pool<2, false, 3, 2><<<g32, 256, 0, s>>>(B, map, A, C, D);                 // map
}

extern "C" void kernel_launch(void* const* d_in, const int* in_sizes, int n_in,
                              void* d_out, int out_size, void* d_ws, size_t ws_size,
                              hipStream_t stream) {
    const float* Rrgb = (const float*)d_in[0];
    const float* Lrgb = (const float*)d_in[1];
    float* out = (float*)d_out;
    float* w = (float*)d_ws;
    const float scale = 1.f / (float)P16N;

    hipMemsetAsync(out, 0, sizeof(float) * (size_t)out_size, stream);

    const size_t stack32 = (size_t)32 * SS;
    const size_t need32 = 5 * stack32 * sizeof(float) + 1024 * sizeof(float);
    if (ws_size >= need32) {
        // 32 stacked planes: [0..16)=R, [16..32)=low
        float* G = w;
        float* A = G + stack32;
        float* B = A + stack32;
        float* C = B + stack32;
        float* D = C + stack32;
        float* partials = D + stack32;
        for (int dir = 0; dir < 2; ++dir) {
            grad_kernel<<<nblk(P16N), 256, 0, stream>>>(Rrgb, G, dir);
            grad_kernel<<<nblk(P16N), 256, 0, stream>>>(Lrgb, G + P16N, dir);
            pipeline(G, A, B, C, D, G, 32, stream);
            reduce1<<<1024, 256, 0, stream>>>(G, G + P16N, partials);
            reduce2<<<1, 256, 0, stream>>>(partials, out, scale, 1024);
        }
    } else {
        // fallback: process R and low separately (16 planes), ~101 MB
        float* G = w;
        float* A = G + (size_t)P16N;
        float* B = A + (size_t)P16N;
        float* C = B + (size_t)P16N;
        float* D = C + (size_t)P16N;
        float* HOLD = D + (size_t)P16N;
        float* partials = HOLD + (size_t)P16N;
        for (int dir = 0; dir < 2; ++dir) {
            grad_kernel<<<nblk(P16N), 256, 0, stream>>>(Rrgb, G, dir);
            pipeline(G, A, B, C, D, HOLD, 16, stream);
            grad_kernel<<<nblk(P16N), 256, 0, stream>>>(Lrgb, G, dir);
            pipeline(G, A, B, C, D, G, 16, stream);
            reduce1<<<1024, 256, 0, stream>>>(HOLD, G, partials);
            reduce2<<<1, 256, 0, stream>>>(partials, out, scale, 1024);
        }
    }
}

// Round 3
// 2311.181 us; speedup vs baseline: 1.3115x; 1.3115x over previous
//
#include <hip/hip_runtime.h>

#define HH 512
#define WW 512
#define SS (HH * WW)          // 262144 elements per plane
#define P16N (16 * SS)        // one input's batch of gray planes

// ---------------- grad (gray fused) ----------------

__device__ __forceinline__ float grayAt(const float* __restrict__ rgb, size_t imgBase, int pix) {
    return 0.299f * rgb[imgBase + pix]
         + 0.587f * rgb[imgBase + SS + pix]
         + 0.114f * rgb[imgBase + 2 * SS + pix];
}

// dir 0 = x (cols), 1 = y (rows). Forward diff, neighbor beyond edge = 0 pad.
__global__ void grad_kernel(const float* __restrict__ rgb, float* __restrict__ dst, int dir) {
    int idx = blockIdx.x * 256 + threadIdx.x;           // [0, P16N)
    int img = idx >> 18;                                // SS = 2^18
    int pix = idx & (SS - 1);
    int i = pix >> 9, j = pix & (WW - 1);
    size_t imgBase = (size_t)img * 3 * SS;
    float a = grayAt(rgb, imgBase, pix);
    float b = 0.f;
    if (dir == 0) { if (j < WW - 1) b = grayAt(rgb, imgBase, pix + 1); }
    else          { if (i < HH - 1) b = grayAt(rgb, imgBase, pix + WW); }
    dst[idx] = a - b;
}

// ---------------- fused separable pool (row+col in one kernel) ----------------
// OP: 0=max, 1=min, 2=avg. Valid-only windows (matches -inf / zero-pad semantics).
// EPI: 0=none, 1=gn1 (v=gmin1; e1=g, e2=gmax1), 2=final map (v=pmin; e1=go, e2=pmax,
//      e3=gn1), 3=abs output.
// TH=8 output rows per block; grid = planes * 64.
template <int OP, bool PREABS, int R, int EPI>
__global__ __launch_bounds__(256) void fused_pool(
    const float* __restrict__ src, float* __restrict__ dst,
    const float* __restrict__ e1, const float* __restrict__ e2,
    const float* __restrict__ e3)
{
    constexpr int TH   = 8;
    constexpr int ROWS = TH + 2 * R;             // <= 24 -> LDS <= 48 KB
    __shared__ float rp[ROWS * WW];

    const int plane = blockIdx.x >> 6;
    const int tile  = blockIdx.x & 63;
    const int i0    = tile * TH;
    const size_t pbase = (size_t)plane * SS;
    const float* sp = src + pbase;
    const int tid = threadIdx.x;

    // ---- Stage A: row pooling into LDS for rows [i0-R, i0+TH-1+R] (clamped) ----
    if (OP == 2) {
        // coalesced span-sliding sums: thread owns 8 consecutive outputs
        for (int s = tid; s < ROWS * 64; s += 256) {
            int rr = s >> 6, spn = s & 63;
            int gi = i0 - R + rr;
            if ((unsigned)gi >= (unsigned)HH) continue;
            const float* rowp = sp + (size_t)gi * WW;
            int j0 = spn << 3;
            int lo = j0 - R; if (lo < 0) lo = 0;
            int hi = j0 + R; if (hi > WW - 1) hi = WW - 1;
            float acc = 0.f;
            for (int jj = lo; jj <= hi; ++jj) {
                float v = rowp[jj]; if (PREABS) v = fabsf(v); acc += v;
            }
            float o[8];
            o[0] = acc;
            #pragma unroll
            for (int d = 1; d < 8; ++d) {
                int j = j0 + d;
                int add = j + R, sub = j - R - 1;
                if (add < WW) { float v = rowp[add]; if (PREABS) v = fabsf(v); acc += v; }
                if (sub >= 0) { float v = rowp[sub]; if (PREABS) v = fabsf(v); acc -= v; }
                o[d] = acc;
            }
            float4* d4 = (float4*)&rp[rr * WW + j0];
            d4[0] = make_float4(o[0], o[1], o[2], o[3]);
            d4[1] = make_float4(o[4], o[5], o[6], o[7]);
        }
    } else {
        // brute-force max/min (<= 9 taps), consecutive lanes -> consecutive j (coalesced)
        for (int idx = tid; idx < ROWS * WW; idx += 256) {
            int rr = idx >> 9, j = idx & (WW - 1);
            int gi = i0 - R + rr;
            if ((unsigned)gi >= (unsigned)HH) continue;
            const float* rowp = sp + (size_t)gi * WW;
            int lo = j - R; if (lo < 0) lo = 0;
            int hi = j + R; if (hi > WW - 1) hi = WW - 1;
            float acc = (OP == 0) ? -3.402823466e38f : 3.402823466e38f;
            for (int jj = lo; jj <= hi; ++jj) {
                float v = rowp[jj]; if (PREABS) v = fabsf(v);
                acc = (OP == 0) ? fmaxf(acc, v) : fminf(acc, v);
            }
            rp[rr * WW + j] = acc;
        }
    }
    __syncthreads();

    // ---- Stage B: column pooling from LDS, TH x 512 outputs ----
    if (OP == 2) {
        for (int j = tid; j < WW; j += 256) {    // 2 columns per thread
            int cw = min(j + R, WW - 1) - max(j - R, 0) + 1;
            float acc = 0.f;
            int glo = max(i0 - R, 0), ghi = min(i0 + R, HH - 1);
            for (int gi = glo; gi <= ghi; ++gi) acc += rp[(gi - (i0 - R)) * WW + j];
            #pragma unroll
            for (int oi = 0; oi < TH; ++oi) {
                int i = i0 + oi;
                if (oi > 0) {
                    int add = i + R, sub = i - R - 1;
                    if (add < HH) acc += rp[(add - (i0 - R)) * WW + j];
                    if (sub >= 0) acc -= rp[(sub - (i0 - R)) * WW + j];
                }
                int ch = min(i + R, HH - 1) - max(i - R, 0) + 1;
                float v = acc / (float)(ch * cw);
                size_t o = pbase + (size_t)i * WW + j;
                if (EPI == 1) {
                    float ga = fabsf(e1[o]);
                    v = (ga - v) / (fabsf(e2[o] - v) + 1e-4f);
                } else if (EPI == 2) {
                    float gn = (e1[o] - v) / (fabsf(e2[o] - v) + 1e-4f);
                    v = (gn + 0.01f) * e3[o];
                } else if (EPI == 3) {
                    v = fabsf(v);
                }
                dst[o] = v;
            }
        }
    } else {
        for (int idx = tid; idx < TH * WW; idx += 256) {
            int oi = idx >> 9, j = idx & (WW - 1);
            int i = i0 + oi;
            int glo = max(i - R, 0), ghi = min(i + R, HH - 1);
            float acc = (OP == 0) ? -3.402823466e38f : 3.402823466e38f;
            for (int gi = glo; gi <= ghi; ++gi) {
                float v = rp[(gi - (i0 - R)) * WW + j];
                acc = (OP == 0) ? fmaxf(acc, v) : fminf(acc, v);
            }
            dst[pbase + (size_t)i * WW + j] = acc;
        }
    }
}

// ---------------- reduction (two-stage, no hot atomics) ----------------

__global__ __launch_bounds__(256) void reduce1(const float* __restrict__ mR,
                                               const float* __restrict__ mL,
                                               float* __restrict__ partials) {
    int tid = blockIdx.x * 256 + threadIdx.x;
    float v = 0.f;
    for (int i = tid; i < P16N; i += 256 * 1024) {
        float a = mR[i], b = mL[i];
        v += a * expf(-10.f * a) * expf(-10.f * b);
    }
    for (int off = 32; off; off >>= 1) v += __shfl_down(v, off);
    __shared__ float lds[4];
    int lane = threadIdx.x & 63, wv = threadIdx.x >> 6;
    if (lane == 0) lds[wv] = v;
    __syncthreads();
    if (threadIdx.x == 0) partials[blockIdx.x] = lds[0] + lds[1] + lds[2] + lds[3];
}

__global__ __launch_bounds__(256) void reduce2(const float* __restrict__ partials,
                                               float* __restrict__ out, float scale, int n) {
    float v = 0.f;
    for (int i = threadIdx.x; i < n; i += 256) v += partials[i];
    for (int off = 32; off; off >>= 1) v += __shfl_down(v, off);
    __shared__ float lds[4];
    int lane = threadIdx.x & 63, wv = threadIdx.x >> 6;
    if (lane == 0) lds[wv] = v;
    __syncthreads();
    if (threadIdx.x == 0) atomicAdd(out, (lds[0] + lds[1] + lds[2] + lds[3]) * scale);
}

// ---------------- host orchestration ----------------

static inline int nblk(int total) { return (total + 255) / 256; }

// G holds g on entry; final per-pixel map written to `map`.
static void pipeline(float* G, float* A, float* B, float* C, float* D, float* map,
                     int planes, hipStream_t s) {
    int g = planes * 64;     // TH=8 tiles
    fused_pool<0, true , 4, 0><<<g, 256, 0, s>>>(G, A, nullptr, nullptr, nullptr); // pmax1=max9|g|
    fused_pool<1, true , 4, 0><<<g, 256, 0, s>>>(G, B, nullptr, nullptr, nullptr); // pmin1=min9|g|
    fused_pool<2, false, 8, 0><<<g, 256, 0, s>>>(A, C, nullptr, nullptr, nullptr); // gmax1=avg17
    fused_pool<2, false, 8, 1><<<g, 256, 0, s>>>(B, D, G, C, nullptr);             // gn1
    fused_pool<2, false, 2, 3><<<g, 256, 0, s>>>(G, A, nullptr, nullptr, nullptr); // go=|avg5 g|
    fused_pool<0, false, 3, 0><<<g, 256, 0, s>>>(A, B, nullptr, nullptr, nullptr); // max7(go)
    fused_pool<2, false, 3, 0><<<g, 256, 0, s>>>(B, C, nullptr, nullptr, nullptr); // pmax=avg7
    fused_pool<1, false, 3, 0><<<g, 256, 0, s>>>(A, B, nullptr, nullptr, nullptr); // min7(go)
    fused_pool<2, false, 3, 2><<<g, 256, 0, s>>>(B, map, A, C, D);                 // map
}

extern "C" void kernel_launch(void* const* d_in, const int* in_sizes, int n_in,
                              void* d_out, int out_size, void* d_ws, size_t ws_size,
                              hipStream_t stream) {
    const float* Rrgb = (const float*)d_in[0];
    const float* Lrgb = (const float*)d_in[1];
    float* out = (float*)d_out;
    float* w = (float*)d_ws;
    const float scale = 1.f / (float)P16N;

    hipMemsetAsync(out, 0, sizeof(float) * (size_t)out_size, stream);

    const size_t stack32 = (size_t)32 * SS;
    const size_t need32 = 5 * stack32 * sizeof(float) + 1024 * sizeof(float);
    if (ws_size >= need32) {
        // 32 stacked planes: [0..16)=R, [16..32)=low
        float* G = w;
        float* A = G + stack32;
        float* B = A + stack32;
        float* C = B + stack32;
        float* D = C + stack32;
        float* partials = D + stack32;
        for (int dir = 0; dir < 2; ++dir) {
            grad_kernel<<<nblk(P16N), 256, 0, stream>>>(Rrgb, G, dir);
            grad_kernel<<<nblk(P16N), 256, 0, stream>>>(Lrgb, G + P16N, dir);
            pipeline(G, A, B, C, D, G, 32, stream);
            reduce1<<<1024, 256, 0, stream>>>(G, G + P16N, partials);
            reduce2<<<1, 256, 0, stream>>>(partials, out, scale, 1024);
        }
    } else {
        // fallback: process R and low separately (16 planes), ~101 MB
        float* G = w;
        float* A = G + (size_t)P16N;
        float* B = A + (size_t)P16N;
        float* C = B + (size_t)P16N;
        float* D = C + (size_t)P16N;
        float* HOLD = D + (size_t)P16N;
        float* partials = HOLD + (size_t)P16N;
        for (int dir = 0; dir < 2; ++dir) {
            grad_kernel<<<nblk(P16N), 256, 0, stream>>>(Rrgb, G, dir);
            pipeline(G, A, B, C, D, HOLD, 16, stream);
            grad_kernel<<<nblk(P16N), 256, 0, stream>>>(Lrgb, G, dir);
            pipeline(G, A, B, C, D, G, 16, stream);
            reduce1<<<1024, 256, 0, stream>>>(HOLD, G, partials);
            reduce2<<<1, 256, 0, stream>>>(partials, out, scale, 1024);
        }
    }
}

// Round 4
// 609.621 us; speedup vs baseline: 4.9720x; 3.7912x over previous
//
#include <hip/hip_runtime.h>

#define HH 512
#define WW 512
#define SS (HH * WW)          // elements per plane
#define P16N (16 * SS)        // one input's batch of gray planes

constexpr float FINF = 3.402823466e38f;

// ---------------- grad (gray fused) ----------------

__device__ __forceinline__ float grayAt(const float* __restrict__ rgb, size_t imgBase, int pix) {
    return 0.299f * rgb[imgBase + pix]
         + 0.587f * rgb[imgBase + SS + pix]
         + 0.114f * rgb[imgBase + 2 * SS + pix];
}

// dir 0 = x (cols), 1 = y (rows). Forward diff, neighbor beyond edge = 0 pad.
__global__ void grad_kernel(const float* __restrict__ rgb, float* __restrict__ dst, int dir) {
    int idx = blockIdx.x * 256 + threadIdx.x;           // [0, P16N)
    int img = idx >> 18;
    int pix = idx & (SS - 1);
    int i = pix >> 9, j = pix & (WW - 1);
    size_t imgBase = (size_t)img * 3 * SS;
    float a = grayAt(rgb, imgBase, pix);
    float b = 0.f;
    if (dir == 0) { if (j < WW - 1) b = grayAt(rgb, imgBase, pix + 1); }
    else          { if (i < HH - 1) b = grayAt(rgb, imgBase, pix + WW); }
    dst[idx] = a - b;
}

// ---------------- dual max+min pool (column-first) ----------------
// Phase 1: vertical max/min via register ring, coalesced float2 row walks.
// Phase 2: horizontal max/min from LDS via register span windows.
template <bool PREABS, int R, int TH>
__global__ __launch_bounds__(256) void dual_pool(const float* __restrict__ src,
                                                 float* __restrict__ dmax,
                                                 float* __restrict__ dmin) {
    constexpr int TILES = HH / TH;
    constexpr int W = 2 * R + 1;
    __shared__ float lmax[TH * WW], lmin[TH * WW];

    const int plane = blockIdx.x / TILES;
    const int tile  = blockIdx.x % TILES;
    const int i0    = tile * TH;
    const size_t pbase = (size_t)plane * SS;
    const float* sp = src + pbase;
    const int t = threadIdx.x;

    float2 rmx[W], rmn[W];
    auto ld = [&](int gi, float2& vx, float2& vn) {
        if ((unsigned)gi < (unsigned)HH) {             // wave-uniform branch
            float2 v = ((const float2*)(sp + (size_t)gi * WW))[t];
            if (PREABS) { v.x = fabsf(v.x); v.y = fabsf(v.y); }
            vx = v; vn = v;
        } else {
            vx = make_float2(-FINF, -FINF); vn = make_float2(FINF, FINF);
        }
    };
    #pragma unroll
    for (int k = 0; k < W; ++k) ld(i0 - R + k, rmx[k], rmn[k]);
    #pragma unroll
    for (int oi = 0; oi < TH; ++oi) {
        if (oi > 0) {
            #pragma unroll
            for (int k = 0; k < W - 1; ++k) { rmx[k] = rmx[k + 1]; rmn[k] = rmn[k + 1]; }
            ld(i0 + oi + R, rmx[W - 1], rmn[W - 1]);
        }
        float2 mx = rmx[0], mn = rmn[0];
        #pragma unroll
        for (int k = 1; k < W; ++k) {
            mx.x = fmaxf(mx.x, rmx[k].x); mx.y = fmaxf(mx.y, rmx[k].y);
            mn.x = fminf(mn.x, rmn[k].x); mn.y = fminf(mn.y, rmn[k].y);
        }
        ((float2*)&lmax[oi * WW])[t] = mx;
        ((float2*)&lmin[oi * WW])[t] = mn;
    }
    __syncthreads();

    // Phase 2: spans of 8 outputs; window regs loaded once per span.
    for (int s = t; s < TH * 64; s += 256) {
        int rr = s >> 6, j0 = (s & 63) << 3;
        float vx[2 * R + 8], vn[2 * R + 8];
        #pragma unroll
        for (int k = 0; k < 2 * R + 8; ++k) {
            int jj = j0 - R + k;
            bool ok = (unsigned)jj < (unsigned)WW;
            vx[k] = ok ? lmax[rr * WW + jj] : -FINF;
            vn[k] = ok ? lmin[rr * WW + jj] :  FINF;
        }
        float ox[8], on[8];
        #pragma unroll
        for (int d = 0; d < 8; ++d) {
            float mx = vx[d], mn = vn[d];
            #pragma unroll
            for (int k = 1; k <= 2 * R; ++k) { mx = fmaxf(mx, vx[d + k]); mn = fminf(mn, vn[d + k]); }
            ox[d] = mx; on[d] = mn;
        }
        size_t o = pbase + (size_t)(i0 + rr) * WW + j0;
        ((float4*)&dmax[o])[0] = make_float4(ox[0], ox[1], ox[2], ox[3]);
        ((float4*)&dmax[o])[1] = make_float4(ox[4], ox[5], ox[6], ox[7]);
        ((float4*)&dmin[o])[0] = make_float4(on[0], on[1], on[2], on[3]);
        ((float4*)&dmin[o])[1] = make_float4(on[4], on[5], on[6], on[7]);
    }
}

// ---------------- avg pool (column-first, valid-count divide) ----------------
// EPI: 0=none, 1=gn1 (v=gmin1; e1=g, e2=gmax1), 2=final map (v=pmin; e1=go,
//      e2=pmax, e3=gn1), 3=abs output.
template <int R, int EPI, int TH>
__global__ __launch_bounds__(256) void avg_pool(const float* __restrict__ src,
                                                float* __restrict__ dst,
                                                const float* __restrict__ e1,
                                                const float* __restrict__ e2,
                                                const float* __restrict__ e3) {
    constexpr int TILES = HH / TH;
    __shared__ float ls[TH * WW];

    const int plane = blockIdx.x / TILES;
    const int tile  = blockIdx.x % TILES;
    const int i0    = tile * TH;
    const size_t pbase = (size_t)plane * SS;
    const float* sp = src + pbase;
    const int t = threadIdx.x;

    auto ld = [&](int gi) -> float2 {
        if ((unsigned)gi < (unsigned)HH)               // wave-uniform branch
            return ((const float2*)(sp + (size_t)gi * WW))[t];
        return make_float2(0.f, 0.f);
    };
    float2 acc = make_float2(0.f, 0.f);
    #pragma unroll
    for (int k = -R; k <= R; ++k) { float2 v = ld(i0 + k); acc.x += v.x; acc.y += v.y; }
    ((float2*)&ls[0])[t] = acc;
    #pragma unroll
    for (int oi = 1; oi < TH; ++oi) {
        float2 a = ld(i0 + oi + R), s = ld(i0 + oi - R - 1);
        acc.x += a.x - s.x; acc.y += a.y - s.y;
        ((float2*)&ls[oi * WW])[t] = acc;
    }
    __syncthreads();

    // Phase 2: horizontal sliding sums over spans of 8; divide by valid count.
    for (int s = t; s < TH * 64; s += 256) {
        int rr = s >> 6, j0 = (s & 63) << 3;
        int i = i0 + rr;
        int ch = min(i + R, HH - 1) - max(i - R, 0) + 1;
        const float* row = &ls[rr * WW];
        int lo = max(j0 - R, 0), hi = min(j0 + R, WW - 1);
        float racc = 0.f;
        for (int jj = lo; jj <= hi; ++jj) racc += row[jj];
        float ov[8];
        #pragma unroll
        for (int d = 0; d < 8; ++d) {
            if (d > 0) {
                int add = j0 + d + R, sub = j0 + d - R - 1;
                if (add < WW) racc += row[add];
                if (sub >= 0) racc -= row[sub];
            }
            int j = j0 + d;
            int cw = min(j + R, WW - 1) - max(j - R, 0) + 1;
            float v = racc / (float)(ch * cw);
            size_t o = pbase + (size_t)i * WW + j;
            if (EPI == 1) {
                float ga = fabsf(e1[o]);
                v = (ga - v) / (fabsf(e2[o] - v) + 1e-4f);
            } else if (EPI == 2) {
                float gn = (e1[o] - v) / (fabsf(e2[o] - v) + 1e-4f);
                v = (gn + 0.01f) * e3[o];
            } else if (EPI == 3) {
                v = fabsf(v);
            }
            ov[d] = v;
        }
        float4* d4 = (float4*)&dst[pbase + (size_t)i * WW + j0];
        d4[0] = make_float4(ov[0], ov[1], ov[2], ov[3]);
        d4[1] = make_float4(ov[4], ov[5], ov[6], ov[7]);
    }
}

// ---------------- reduction (two-stage, no hot atomics) ----------------

__global__ __launch_bounds__(256) void reduce1(const float* __restrict__ mR,
                                               const float* __restrict__ mL,
                                               float* __restrict__ partials) {
    int tid = blockIdx.x * 256 + threadIdx.x;
    float v = 0.f;
    for (int i = tid; i < P16N; i += 256 * 1024) {
        float a = mR[i], b = mL[i];
        v += a * expf(-10.f * a) * expf(-10.f * b);
    }
    for (int off = 32; off; off >>= 1) v += __shfl_down(v, off);
    __shared__ float lds[4];
    int lane = threadIdx.x & 63, wv = threadIdx.x >> 6;
    if (lane == 0) lds[wv] = v;
    __syncthreads();
    if (threadIdx.x == 0) partials[blockIdx.x] = lds[0] + lds[1] + lds[2] + lds[3];
}

__global__ __launch_bounds__(256) void reduce2(const float* __restrict__ partials,
                                               float* __restrict__ out, float scale, int n) {
    float v = 0.f;
    for (int i = threadIdx.x; i < n; i += 256) v += partials[i];
    for (int off = 32; off; off >>= 1) v += __shfl_down(v, off);
    __shared__ float lds[4];
    int lane = threadIdx.x & 63, wv = threadIdx.x >> 6;
    if (lane == 0) lds[wv] = v;
    __syncthreads();
    if (threadIdx.x == 0) atomicAdd(out, (lds[0] + lds[1] + lds[2] + lds[3]) * scale);
}

// ---------------- host orchestration ----------------

static inline int nblk(int total) { return (total + 255) / 256; }

// G holds g on entry; final per-pixel map written to `map` (must not alias G,A,C,D).
static void pipeline(float* G, float* A, float* B, float* C, float* D, float* map,
                     int planes, hipStream_t s) {
    int gd = planes * (HH / 8);    // dual pools, TH=8
    int ga = planes * (HH / 16);   // avg pools,  TH=16
    dual_pool<true , 4, 8><<<gd, 256, 0, s>>>(G, A, B);             // A=max9|g|, B=min9|g|
    avg_pool <8, 0, 16><<<ga, 256, 0, s>>>(A, C, nullptr, nullptr, nullptr); // C=gmax1
    avg_pool <8, 1, 16><<<ga, 256, 0, s>>>(B, D, G, C, nullptr);    // D=gn1
    avg_pool <2, 3, 16><<<ga, 256, 0, s>>>(G, A, nullptr, nullptr, nullptr); // A=go (G free)
    dual_pool<false, 3, 8><<<gd, 256, 0, s>>>(A, B, C);             // B=max7(go), C=min7(go)
    avg_pool <3, 0, 16><<<ga, 256, 0, s>>>(B, G, nullptr, nullptr, nullptr); // G=pmax
    avg_pool <3, 2, 16><<<ga, 256, 0, s>>>(C, map, A, G, D);        // map
}

extern "C" void kernel_launch(void* const* d_in, const int* in_sizes, int n_in,
                              void* d_out, int out_size, void* d_ws, size_t ws_size,
                              hipStream_t stream) {
    const float* Rrgb = (const float*)d_in[0];
    const float* Lrgb = (const float*)d_in[1];
    float* out = (float*)d_out;
    float* w = (float*)d_ws;
    const float scale = 1.f / (float)P16N;

    hipMemsetAsync(out, 0, sizeof(float) * (size_t)out_size, stream);

    const size_t stack32 = (size_t)32 * SS;
    const size_t need32 = 5 * stack32 * sizeof(float) + 1024 * sizeof(float);
    if (ws_size >= need32) {
        // 32 stacked planes: [0..16)=R, [16..32)=low
        float* G = w;
        float* A = G + stack32;
        float* B = A + stack32;
        float* C = B + stack32;
        float* D = C + stack32;
        float* partials = D + stack32;
        for (int dir = 0; dir < 2; ++dir) {
            grad_kernel<<<nblk(P16N), 256, 0, stream>>>(Rrgb, G, dir);
            grad_kernel<<<nblk(P16N), 256, 0, stream>>>(Lrgb, G + P16N, dir);
            pipeline(G, A, B, C, D, B, 32, stream);      // map -> B (free by then)
            reduce1<<<1024, 256, 0, stream>>>(B, B + P16N, partials);
            reduce2<<<1, 256, 0, stream>>>(partials, out, scale, 1024);
        }
    } else {
        // fallback: process R and low separately (16 planes)
        float* G = w;
        float* A = G + (size_t)P16N;
        float* B = A + (size_t)P16N;
        float* C = B + (size_t)P16N;
        float* D = C + (size_t)P16N;
        float* HOLD = D + (size_t)P16N;
        float* partials = HOLD + (size_t)P16N;
        for (int dir = 0; dir < 2; ++dir) {
            grad_kernel<<<nblk(P16N), 256, 0, stream>>>(Rrgb, G, dir);
            pipeline(G, A, B, C, D, HOLD, 16, stream);
            grad_kernel<<<nblk(P16N), 256, 0, stream>>>(Lrgb, G, dir);
            pipeline(G, A, B, C, D, B, 16, stream);
            reduce1<<<1024, 256, 0, stream>>>(HOLD, B, partials);
            reduce2<<<1, 256, 0, stream>>>(partials, out, scale, 1024);
        }
    }
}

// Round 5
// 507.062 us; speedup vs baseline: 5.9777x; 1.2023x over previous
//
#include <hip/hip_runtime.h>

#define HH 512
#define WW 512
#define SS (HH * WW)          // elements per plane
#define P16N (16 * SS)        // one input's batch of gray planes
#define PADW 576              // skewed LDS row: addr(j) = j + (j>>3), max 574

constexpr float FINF = 3.402823466e38f;

__device__ __forceinline__ int swz(int j) { return j + (j >> 3); }

// ---------------- grad (gray fused, 4 px/thread) ----------------

__global__ __launch_bounds__(256) void grad_kernel(const float* __restrict__ rgb,
                                                   float* __restrict__ dst, int dir) {
    int sp = blockIdx.x * 256 + threadIdx.x;       // span of 4 px
    int idx = sp << 2;                             // [0, P16N)
    int img = idx >> 18;
    int pix = idx & (SS - 1);
    int i = pix >> 9, j0 = pix & (WW - 1);
    const float* p0 = rgb + (size_t)img * 3 * SS + pix;

    float4 r = *(const float4*)p0;
    float4 g = *(const float4*)(p0 + SS);
    float4 b = *(const float4*)(p0 + 2 * SS);
    float4 gray = make_float4(0.299f * r.x + 0.587f * g.x + 0.114f * b.x,
                              0.299f * r.y + 0.587f * g.y + 0.114f * b.y,
                              0.299f * r.z + 0.587f * g.z + 0.114f * b.z,
                              0.299f * r.w + 0.587f * g.w + 0.114f * b.w);
    float4 ngray;
    if (dir == 0) {
        float rs = 0.f, gs = 0.f, bs = 0.f;
        if (j0 + 4 < WW) { rs = p0[4]; gs = p0[SS + 4]; bs = p0[2 * SS + 4]; }
        ngray = make_float4(0.299f * r.y + 0.587f * g.y + 0.114f * b.y,
                            0.299f * r.z + 0.587f * g.z + 0.114f * b.z,
                            0.299f * r.w + 0.587f * g.w + 0.114f * b.w,
                            0.299f * rs  + 0.587f * gs  + 0.114f * bs);
    } else {
        if (i < HH - 1) {
            float4 r2 = *(const float4*)(p0 + WW);
            float4 g2 = *(const float4*)(p0 + SS + WW);
            float4 b2 = *(const float4*)(p0 + 2 * SS + WW);
            ngray = make_float4(0.299f * r2.x + 0.587f * g2.x + 0.114f * b2.x,
                                0.299f * r2.y + 0.587f * g2.y + 0.114f * b2.y,
                                0.299f * r2.z + 0.587f * g2.z + 0.114f * b2.z,
                                0.299f * r2.w + 0.587f * g2.w + 0.114f * b2.w);
        } else {
            ngray = make_float4(0.f, 0.f, 0.f, 0.f);
        }
    }
    *(float4*)(dst + idx) = make_float4(gray.x - ngray.x, gray.y - ngray.y,
                                        gray.z - ngray.z, gray.w - ngray.w);
}

// ---------------- dual max+min pool (column-first, skewed LDS) ----------------
template <bool PREABS, int R, int TH>
__global__ __launch_bounds__(256) void dual_pool(const float* __restrict__ src,
                                                 float* __restrict__ dmax,
                                                 float* __restrict__ dmin) {
    constexpr int TILES = HH / TH;
    constexpr int W = 2 * R + 1;
    __shared__ float lmax[TH * PADW], lmin[TH * PADW];

    const int plane = blockIdx.x / TILES;
    const int tile  = blockIdx.x % TILES;
    const int i0    = tile * TH;
    const size_t pbase = (size_t)plane * SS;
    const float* sp = src + pbase;
    const int t = threadIdx.x;

    float2 rmx[W], rmn[W];
    auto ld = [&](int gi, float2& vx, float2& vn) {
        if ((unsigned)gi < (unsigned)HH) {             // wave-uniform branch
            float2 v = ((const float2*)(sp + (size_t)gi * WW))[t];
            if (PREABS) { v.x = fabsf(v.x); v.y = fabsf(v.y); }
            vx = v; vn = v;
        } else {
            vx = make_float2(-FINF, -FINF); vn = make_float2(FINF, FINF);
        }
    };
    #pragma unroll
    for (int k = 0; k < W; ++k) ld(i0 - R + k, rmx[k], rmn[k]);
    const int c = 2 * t, ca = swz(2 * t);              // ca+1 == swz(c+1), c even
    #pragma unroll
    for (int oi = 0; oi < TH; ++oi) {
        if (oi > 0) {
            #pragma unroll
            for (int k = 0; k < W - 1; ++k) { rmx[k] = rmx[k + 1]; rmn[k] = rmn[k + 1]; }
            ld(i0 + oi + R, rmx[W - 1], rmn[W - 1]);
        }
        float2 mx = rmx[0], mn = rmn[0];
        #pragma unroll
        for (int k = 1; k < W; ++k) {
            mx.x = fmaxf(mx.x, rmx[k].x); mx.y = fmaxf(mx.y, rmx[k].y);
            mn.x = fminf(mn.x, rmn[k].x); mn.y = fminf(mn.y, rmn[k].y);
        }
        lmax[oi * PADW + ca] = mx.x; lmax[oi * PADW + ca + 1] = mx.y;
        lmin[oi * PADW + ca] = mn.x; lmin[oi * PADW + ca + 1] = mn.y;
    }
    __syncthreads();

    // Phase 2: spans of 8 outputs; skewed reads are conflict-free (stride 9).
    for (int s = t; s < TH * 64; s += 256) {
        int rr = s >> 6, j0 = (s & 63) << 3;
        const float* rx = &lmax[rr * PADW];
        const float* rn = &lmin[rr * PADW];
        float vx[2 * R + 8], vn[2 * R + 8];
        #pragma unroll
        for (int k = 0; k < 2 * R + 8; ++k) {
            int jj = j0 - R + k;
            bool ok = (unsigned)jj < (unsigned)WW;
            int jc = swz(min(max(jj, 0), WW - 1));
            vx[k] = ok ? rx[jc] : -FINF;
            vn[k] = ok ? rn[jc] :  FINF;
        }
        float ox[8], on[8];
        #pragma unroll
        for (int d = 0; d < 8; ++d) {
            float mx = vx[d], mn = vn[d];
            #pragma unroll
            for (int k = 1; k <= 2 * R; ++k) { mx = fmaxf(mx, vx[d + k]); mn = fminf(mn, vn[d + k]); }
            ox[d] = mx; on[d] = mn;
        }
        size_t o = pbase + (size_t)(i0 + rr) * WW + j0;
        ((float4*)&dmax[o])[0] = make_float4(ox[0], ox[1], ox[2], ox[3]);
        ((float4*)&dmax[o])[1] = make_float4(ox[4], ox[5], ox[6], ox[7]);
        ((float4*)&dmin[o])[0] = make_float4(on[0], on[1], on[2], on[3]);
        ((float4*)&dmin[o])[1] = make_float4(on[4], on[5], on[6], on[7]);
    }
}

// ---------------- avg pool (column-first, skewed LDS, valid-count divide) ----------------
// EPI: 0=none, 1=gn1 (v=gmin1; e1=g, e2=gmax1), 2=final map (v=pmin; e1=go,
//      e2=pmax, e3=gn1), 3=abs output.
template <int R, int EPI, int TH>
__global__ __launch_bounds__(256) void avg_pool(const float* __restrict__ src,
                                                float* __restrict__ dst,
                                                const float* __restrict__ e1,
                                                const float* __restrict__ e2,
                                                const float* __restrict__ e3) {
    constexpr int TILES = HH / TH;
    __shared__ float ls[TH * PADW];

    const int plane = blockIdx.x / TILES;
    const int tile  = blockIdx.x % TILES;
    const int i0    = tile * TH;
    const size_t pbase = (size_t)plane * SS;
    const float* sp = src + pbase;
    const int t = threadIdx.x;

    auto ld = [&](int gi) -> float2 {
        if ((unsigned)gi < (unsigned)HH)               // wave-uniform branch
            return ((const float2*)(sp + (size_t)gi * WW))[t];
        return make_float2(0.f, 0.f);
    };
    float2 acc = make_float2(0.f, 0.f);
    #pragma unroll
    for (int k = -R; k <= R; ++k) { float2 v = ld(i0 + k); acc.x += v.x; acc.y += v.y; }
    const int ca = swz(2 * t);
    ls[ca] = acc.x; ls[ca + 1] = acc.y;
    #pragma unroll
    for (int oi = 1; oi < TH; ++oi) {
        float2 a = ld(i0 + oi + R), s = ld(i0 + oi - R - 1);
        acc.x += a.x - s.x; acc.y += a.y - s.y;
        ls[oi * PADW + ca] = acc.x; ls[oi * PADW + ca + 1] = acc.y;
    }
    __syncthreads();

    // Phase 2: horizontal sliding sums over spans of 8; skewed reads conflict-free.
    for (int s = t; s < TH * 64; s += 256) {
        int rr = s >> 6, j0 = (s & 63) << 3;
        int i = i0 + rr;
        int ch = min(i + R, HH - 1) - max(i - R, 0) + 1;
        const float* row = &ls[rr * PADW];
        size_t rowbase = pbase + (size_t)i * WW + j0;

        float4 a0, a1, b0, b1, c0, c1;
        if (EPI == 1) {
            a0 = ((const float4*)(e1 + rowbase))[0]; a1 = ((const float4*)(e1 + rowbase))[1];
            b0 = ((const float4*)(e2 + rowbase))[0]; b1 = ((const float4*)(e2 + rowbase))[1];
        } else if (EPI == 2) {
            a0 = ((const float4*)(e1 + rowbase))[0]; a1 = ((const float4*)(e1 + rowbase))[1];
            b0 = ((const float4*)(e2 + rowbase))[0]; b1 = ((const float4*)(e2 + rowbase))[1];
            c0 = ((const float4*)(e3 + rowbase))[0]; c1 = ((const float4*)(e3 + rowbase))[1];
        }
        const float* ea = (const float*)&a0;   // a0,a1 contiguous? build arrays instead
        float e1v[8], e2v[8], e3v[8];
        if (EPI == 1 || EPI == 2) {
            e1v[0]=a0.x; e1v[1]=a0.y; e1v[2]=a0.z; e1v[3]=a0.w;
            e1v[4]=a1.x; e1v[5]=a1.y; e1v[6]=a1.z; e1v[7]=a1.w;
            e2v[0]=b0.x; e2v[1]=b0.y; e2v[2]=b0.z; e2v[3]=b0.w;
            e2v[4]=b1.x; e2v[5]=b1.y; e2v[6]=b1.z; e2v[7]=b1.w;
        }
        if (EPI == 2) {
            e3v[0]=c0.x; e3v[1]=c0.y; e3v[2]=c0.z; e3v[3]=c0.w;
            e3v[4]=c1.x; e3v[5]=c1.y; e3v[6]=c1.z; e3v[7]=c1.w;
        }
        (void)ea;

        int lo = max(j0 - R, 0), hi = min(j0 + R, WW - 1);
        float racc = 0.f;
        for (int jj = lo; jj <= hi; ++jj) racc += row[swz(jj)];
        float ov[8];
        #pragma unroll
        for (int d = 0; d < 8; ++d) {
            if (d > 0) {
                int add = j0 + d + R, sub = j0 + d - R - 1;
                if (add < WW) racc += row[swz(add)];
                if (sub >= 0) racc -= row[swz(sub)];
            }
            int j = j0 + d;
            int cw = min(j + R, WW - 1) - max(j - R, 0) + 1;
            float v = racc / (float)(ch * cw);
            if (EPI == 1) {
                float ga = fabsf(e1v[d]);
                v = (ga - v) / (fabsf(e2v[d] - v) + 1e-4f);
            } else if (EPI == 2) {
                float gn = (e1v[d] - v) / (fabsf(e2v[d] - v) + 1e-4f);
                v = (gn + 0.01f) * e3v[d];
            } else if (EPI == 3) {
                v = fabsf(v);
            }
            ov[d] = v;
        }
        float4* d4 = (float4*)&dst[rowbase];
        d4[0] = make_float4(ov[0], ov[1], ov[2], ov[3]);
        d4[1] = make_float4(ov[4], ov[5], ov[6], ov[7]);
    }
}

// ---------------- reduction (two-stage, no hot atomics) ----------------

__global__ __launch_bounds__(256) void reduce1(const float* __restrict__ mR,
                                               const float* __restrict__ mL,
                                               float* __restrict__ partials) {
    int tid = blockIdx.x * 256 + threadIdx.x;
    float v = 0.f;
    for (int i = tid; i < P16N; i += 256 * 1024) {
        float a = mR[i], b = mL[i];
        v += a * expf(-10.f * a) * expf(-10.f * b);
    }
    for (int off = 32; off; off >>= 1) v += __shfl_down(v, off);
    __shared__ float lds[4];
    int lane = threadIdx.x & 63, wv = threadIdx.x >> 6;
    if (lane == 0) lds[wv] = v;
    __syncthreads();
    if (threadIdx.x == 0) partials[blockIdx.x] = lds[0] + lds[1] + lds[2] + lds[3];
}

__global__ __launch_bounds__(256) void reduce2(const float* __restrict__ partials,
                                               float* __restrict__ out, float scale, int n) {
    float v = 0.f;
    for (int i = threadIdx.x; i < n; i += 256) v += partials[i];
    for (int off = 32; off; off >>= 1) v += __shfl_down(v, off);
    __shared__ float lds[4];
    int lane = threadIdx.x & 63, wv = threadIdx.x >> 6;
    if (lane == 0) lds[wv] = v;
    __syncthreads();
    if (threadIdx.x == 0) atomicAdd(out, (lds[0] + lds[1] + lds[2] + lds[3]) * scale);
}

// ---------------- host orchestration ----------------

static inline int nblk(int total) { return (total + 255) / 256; }

// G holds g on entry; final per-pixel map written to `map` (must not alias G,A,C,D).
static void pipeline(float* G, float* A, float* B, float* C, float* D, float* map,
                     int planes, hipStream_t s) {
    int gd = planes * (HH / 8);    // dual pools, TH=8
    int ga = planes * (HH / 16);   // avg pools,  TH=16
    dual_pool<true , 4, 8><<<gd, 256, 0, s>>>(G, A, B);             // A=max9|g|, B=min9|g|
    avg_pool <8, 0, 16><<<ga, 256, 0, s>>>(A, C, nullptr, nullptr, nullptr); // C=gmax1
    avg_pool <8, 1, 16><<<ga, 256, 0, s>>>(B, D, G, C, nullptr);    // D=gn1
    avg_pool <2, 3, 16><<<ga, 256, 0, s>>>(G, A, nullptr, nullptr, nullptr); // A=go (G free)
    dual_pool<false, 3, 8><<<gd, 256, 0, s>>>(A, B, C);             // B=max7(go), C=min7(go)
    avg_pool <3, 0, 16><<<ga, 256, 0, s>>>(B, G, nullptr, nullptr, nullptr); // G=pmax
    avg_pool <3, 2, 16><<<ga, 256, 0, s>>>(C, map, A, G, D);        // map
}

extern "C" void kernel_launch(void* const* d_in, const int* in_sizes, int n_in,
                              void* d_out, int out_size, void* d_ws, size_t ws_size,
                              hipStream_t stream) {
    const float* Rrgb = (const float*)d_in[0];
    const float* Lrgb = (const float*)d_in[1];
    float* out = (float*)d_out;
    float* w = (float*)d_ws;
    const float scale = 1.f / (float)P16N;

    hipMemsetAsync(out, 0, sizeof(float) * (size_t)out_size, stream);

    const size_t stack32 = (size_t)32 * SS;
    const size_t need32 = 5 * stack32 * sizeof(float) + 1024 * sizeof(float);
    if (ws_size >= need32) {
        // 32 stacked planes: [0..16)=R, [16..32)=low
        float* G = w;
        float* A = G + stack32;
        float* B = A + stack32;
        float* C = B + stack32;
        float* D = C + stack32;
        float* partials = D + stack32;
        for (int dir = 0; dir < 2; ++dir) {
            grad_kernel<<<nblk(P16N) / 4, 256, 0, stream>>>(Rrgb, G, dir);
            grad_kernel<<<nblk(P16N) / 4, 256, 0, stream>>>(Lrgb, G + P16N, dir);
            pipeline(G, A, B, C, D, B, 32, stream);      // map -> B (free by then)
            reduce1<<<1024, 256, 0, stream>>>(B, B + P16N, partials);
            reduce2<<<1, 256, 0, stream>>>(partials, out, scale, 1024);
        }
    } else {
        // fallback: process R and low separately (16 planes)
        float* G = w;
        float* A = G + (size_t)P16N;
        float* B = A + (size_t)P16N;
        float* C = B + (size_t)P16N;
        float* D = C + (size_t)P16N;
        float* HOLD = D + (size_t)P16N;
        float* partials = HOLD + (size_t)P16N;
        for (int dir = 0; dir < 2; ++dir) {
            grad_kernel<<<nblk(P16N) / 4, 256, 0, stream>>>(Rrgb, G, dir);
            pipeline(G, A, B, C, D, HOLD, 16, stream);
            grad_kernel<<<nblk(P16N) / 4, 256, 0, stream>>>(Lrgb, G, dir);
            pipeline(G, A, B, C, D, B, 16, stream);
            reduce1<<<1024, 256, 0, stream>>>(HOLD, B, partials);
            reduce2<<<1, 256, 0, stream>>>(partials, out, scale, 1024);
        }
    }
}

// Round 6
// 427.615 us; speedup vs baseline: 7.0883x; 1.1858x over previous
//
#include <hip/hip_runtime.h>

#define HH 512
#define WW 512
#define SS (HH * WW)          // elements per plane (2^18)
#define P16N (16 * SS)        // 16 planes (2^22)
#define PADW 576              // skewed LDS row: addr(j) = j + (j>>3)

constexpr float FINF = 3.402823466e38f;

__device__ __forceinline__ int swz(int j) { return j + (j >> 3); }

__device__ __forceinline__ float gray1(float r, float g, float b) {
    return 0.299f * r + 0.587f * g + 0.114f * b;
}

// ---------------- grad (gray fused, both dirs, 4 px/thread) ----------------
// dirsel: 2 = write gx->plane gxp0+img and gy->plane gyp0+img; 0 = gx only; 1 = gy only.
__global__ __launch_bounds__(256) void grad_both(const float* __restrict__ rgb,
                                                 float* __restrict__ dst,
                                                 int gxp0, int gyp0, int dirsel) {
    int sp = blockIdx.x * 256 + threadIdx.x;
    int idx = sp << 2;                             // [0, P16N)
    int img = idx >> 18;
    int pix = idx & (SS - 1);
    int i = pix >> 9, j0 = pix & (WW - 1);
    const float* p0 = rgb + (size_t)img * 3 * SS + pix;

    float4 r = *(const float4*)p0;
    float4 g = *(const float4*)(p0 + SS);
    float4 b = *(const float4*)(p0 + 2 * SS);
    float4 gy4 = make_float4(gray1(r.x, g.x, b.x), gray1(r.y, g.y, b.y),
                             gray1(r.z, g.z, b.z), gray1(r.w, g.w, b.w));
    if (dirsel != 1) {
        float grs = 0.f;
        if (j0 + 4 < WW) grs = gray1(p0[4], p0[SS + 4], p0[2 * SS + 4]);
        float4 gx = make_float4(gy4.x - gy4.y, gy4.y - gy4.z, gy4.z - gy4.w, gy4.w - grs);
        *(float4*)(dst + (size_t)(gxp0 + img) * SS + pix) = gx;
    }
    if (dirsel != 0) {
        float4 gd = make_float4(0.f, 0.f, 0.f, 0.f);
        if (i < HH - 1) {
            float4 r2 = *(const float4*)(p0 + WW);
            float4 g2 = *(const float4*)(p0 + SS + WW);
            float4 b2 = *(const float4*)(p0 + 2 * SS + WW);
            gd = make_float4(gray1(r2.x, g2.x, b2.x), gray1(r2.y, g2.y, b2.y),
                             gray1(r2.z, g2.z, b2.z), gray1(r2.w, g2.w, b2.w));
        }
        float4 gy = make_float4(gy4.x - gd.x, gy4.y - gd.y, gy4.z - gd.z, gy4.w - gd.w);
        *(float4*)(dst + (size_t)(gyp0 + img) * SS + pix) = gy;
    }
}

// ---------------- dual max+min pool (column-first, skewed LDS) ----------------
template <bool PREABS, int R, int TH>
__global__ __launch_bounds__(256) void dual_pool(const float* __restrict__ src,
                                                 float* __restrict__ dmax,
                                                 float* __restrict__ dmin) {
    constexpr int TILES = HH / TH;
    constexpr int W = 2 * R + 1;
    __shared__ float lmax[TH * PADW], lmin[TH * PADW];

    const int plane = blockIdx.x / TILES;
    const int tile  = blockIdx.x % TILES;
    const int i0    = tile * TH;
    const size_t pbase = (size_t)plane * SS;
    const float* sp = src + pbase;
    const int t = threadIdx.x;

    float2 rmx[W], rmn[W];
    auto ld = [&](int gi, float2& vx, float2& vn) {
        if ((unsigned)gi < (unsigned)HH) {             // wave-uniform branch
            float2 v = ((const float2*)(sp + (size_t)gi * WW))[t];
            if (PREABS) { v.x = fabsf(v.x); v.y = fabsf(v.y); }
            vx = v; vn = v;
        } else {
            vx = make_float2(-FINF, -FINF); vn = make_float2(FINF, FINF);
        }
    };
    #pragma unroll
    for (int k = 0; k < W; ++k) ld(i0 - R + k, rmx[k], rmn[k]);
    const int ca = swz(2 * t);                         // ca+1 == swz(2t+1)
    #pragma unroll
    for (int oi = 0; oi < TH; ++oi) {
        if (oi > 0) {
            #pragma unroll
            for (int k = 0; k < W - 1; ++k) { rmx[k] = rmx[k + 1]; rmn[k] = rmn[k + 1]; }
            ld(i0 + oi + R, rmx[W - 1], rmn[W - 1]);
        }
        float2 mx = rmx[0], mn = rmn[0];
        #pragma unroll
        for (int k = 1; k < W; ++k) {
            mx.x = fmaxf(mx.x, rmx[k].x); mx.y = fmaxf(mx.y, rmx[k].y);
            mn.x = fminf(mn.x, rmn[k].x); mn.y = fminf(mn.y, rmn[k].y);
        }
        lmax[oi * PADW + ca] = mx.x; lmax[oi * PADW + ca + 1] = mx.y;
        lmin[oi * PADW + ca] = mn.x; lmin[oi * PADW + ca + 1] = mn.y;
    }
    __syncthreads();

    for (int s = t; s < TH * 64; s += 256) {
        int rr = s >> 6, j0 = (s & 63) << 3;
        const float* rx = &lmax[rr * PADW];
        const float* rn = &lmin[rr * PADW];
        float vx[2 * R + 8], vn[2 * R + 8];
        #pragma unroll
        for (int k = 0; k < 2 * R + 8; ++k) {
            int jj = j0 - R + k;
            bool ok = (unsigned)jj < (unsigned)WW;
            int jc = swz(min(max(jj, 0), WW - 1));
            vx[k] = ok ? rx[jc] : -FINF;
            vn[k] = ok ? rn[jc] :  FINF;
        }
        float ox[8], on[8];
        #pragma unroll
        for (int d = 0; d < 8; ++d) {
            float mx = vx[d], mn = vn[d];
            #pragma unroll
            for (int k = 1; k <= 2 * R; ++k) { mx = fmaxf(mx, vx[d + k]); mn = fminf(mn, vn[d + k]); }
            ox[d] = mx; on[d] = mn;
        }
        size_t o = pbase + (size_t)(i0 + rr) * WW + j0;
        ((float4*)&dmax[o])[0] = make_float4(ox[0], ox[1], ox[2], ox[3]);
        ((float4*)&dmax[o])[1] = make_float4(ox[4], ox[5], ox[6], ox[7]);
        ((float4*)&dmin[o])[0] = make_float4(on[0], on[1], on[2], on[3]);
        ((float4*)&dmin[o])[1] = make_float4(on[4], on[5], on[6], on[7]);
    }
}

// ---------------- single avg pool (EPI=3: abs output) ----------------
template <int R, int TH>
__global__ __launch_bounds__(256) void avg_abs_pool(const float* __restrict__ src,
                                                    float* __restrict__ dst) {
    constexpr int TILES = HH / TH;
    __shared__ float ls[TH * PADW];
    const int plane = blockIdx.x / TILES;
    const int tile  = blockIdx.x % TILES;
    const int i0    = tile * TH;
    const size_t pbase = (size_t)plane * SS;
    const float* sp = src + pbase;
    const int t = threadIdx.x;

    auto ld = [&](int gi) -> float2 {
        if ((unsigned)gi < (unsigned)HH) return ((const float2*)(sp + (size_t)gi * WW))[t];
        return make_float2(0.f, 0.f);
    };
    float2 acc = make_float2(0.f, 0.f);
    #pragma unroll
    for (int k = -R; k <= R; ++k) { float2 v = ld(i0 + k); acc.x += v.x; acc.y += v.y; }
    const int ca = swz(2 * t);
    ls[ca] = acc.x; ls[ca + 1] = acc.y;
    #pragma unroll
    for (int oi = 1; oi < TH; ++oi) {
        float2 a = ld(i0 + oi + R), s = ld(i0 + oi - R - 1);
        acc.x += a.x - s.x; acc.y += a.y - s.y;
        ls[oi * PADW + ca] = acc.x; ls[oi * PADW + ca + 1] = acc.y;
    }
    __syncthreads();

    for (int s = t; s < TH * 64; s += 256) {
        int rr = s >> 6, j0 = (s & 63) << 3;
        int i = i0 + rr;
        int ch = min(i + R, HH - 1) - max(i - R, 0) + 1;
        const float* row = &ls[rr * PADW];
        int lo = max(j0 - R, 0), hi = min(j0 + R, WW - 1);
        float racc = 0.f;
        for (int jj = lo; jj <= hi; ++jj) racc += row[swz(jj)];
        float ov[8];
        #pragma unroll
        for (int d = 0; d < 8; ++d) {
            if (d > 0) {
                int add = j0 + d + R, sub = j0 + d - R - 1;
                if (add < WW) racc += row[swz(add)];
                if (sub >= 0) racc -= row[swz(sub)];
            }
            int j = j0 + d;
            int cw = min(j + R, WW - 1) - max(j - R, 0) + 1;
            ov[d] = fabsf(racc / (float)(ch * cw));
        }
        float4* d4 = (float4*)&dst[pbase + (size_t)i * WW + j0];
        d4[0] = make_float4(ov[0], ov[1], ov[2], ov[3]);
        d4[1] = make_float4(ov[4], ov[5], ov[6], ov[7]);
    }
}

// ---------------- dual-input avg pool + combining epilogue ----------------
// v1 = avg(s1), v2 = avg(s2) at each pixel.
// EPI 1 (gn1): out = (|e1| - v2)/(|v1 - v2| + 1e-4)         [e1 = g]
// EPI 2 (map): out = ((e1 - v2)/(|v1 - v2| + 1e-4) + 0.01) * e2   [e1 = go, e2 = gn1]
// dst may alias e1/e2 (read own pixels before write, same thread).
template <int R, int EPI, int TH>
__global__ __launch_bounds__(256) void davg_pool(const float* __restrict__ s1,
                                                 const float* __restrict__ s2,
                                                 const float* __restrict__ e1,
                                                 const float* __restrict__ e2,
                                                 float* __restrict__ dst) {
    constexpr int TILES = HH / TH;
    __shared__ float l1[TH * PADW], l2[TH * PADW];
    const int plane = blockIdx.x / TILES;
    const int tile  = blockIdx.x % TILES;
    const int i0    = tile * TH;
    const size_t pbase = (size_t)plane * SS;
    const float* sp1 = s1 + pbase;
    const float* sp2 = s2 + pbase;
    const int t = threadIdx.x;

    auto ld = [&](const float* sp, int gi) -> float2 {
        if ((unsigned)gi < (unsigned)HH) return ((const float2*)(sp + (size_t)gi * WW))[t];
        return make_float2(0.f, 0.f);
    };
    float2 a1 = make_float2(0.f, 0.f), a2 = make_float2(0.f, 0.f);
    #pragma unroll
    for (int k = -R; k <= R; ++k) {
        float2 v = ld(sp1, i0 + k); a1.x += v.x; a1.y += v.y;
        float2 w = ld(sp2, i0 + k); a2.x += w.x; a2.y += w.y;
    }
    const int ca = swz(2 * t);
    l1[ca] = a1.x; l1[ca + 1] = a1.y;
    l2[ca] = a2.x; l2[ca + 1] = a2.y;
    #pragma unroll
    for (int oi = 1; oi < TH; ++oi) {
        float2 p = ld(sp1, i0 + oi + R), q = ld(sp1, i0 + oi - R - 1);
        a1.x += p.x - q.x; a1.y += p.y - q.y;
        float2 u = ld(sp2, i0 + oi + R), w = ld(sp2, i0 + oi - R - 1);
        a2.x += u.x - w.x; a2.y += u.y - w.y;
        l1[oi * PADW + ca] = a1.x; l1[oi * PADW + ca + 1] = a1.y;
        l2[oi * PADW + ca] = a2.x; l2[oi * PADW + ca + 1] = a2.y;
    }
    __syncthreads();

    for (int s = t; s < TH * 64; s += 256) {
        int rr = s >> 6, j0 = (s & 63) << 3;
        int i = i0 + rr;
        int ch = min(i + R, HH - 1) - max(i - R, 0) + 1;
        const float* r1 = &l1[rr * PADW];
        const float* r2 = &l2[rr * PADW];
        size_t rowbase = pbase + (size_t)i * WW + j0;

        float e1v[8], e2v[8];
        {
            float4 a0 = ((const float4*)(e1 + rowbase))[0];
            float4 a1q = ((const float4*)(e1 + rowbase))[1];
            e1v[0]=a0.x; e1v[1]=a0.y; e1v[2]=a0.z; e1v[3]=a0.w;
            e1v[4]=a1q.x; e1v[5]=a1q.y; e1v[6]=a1q.z; e1v[7]=a1q.w;
        }
        if (EPI == 2) {
            float4 b0 = ((const float4*)(e2 + rowbase))[0];
            float4 b1q = ((const float4*)(e2 + rowbase))[1];
            e2v[0]=b0.x; e2v[1]=b0.y; e2v[2]=b0.z; e2v[3]=b0.w;
            e2v[4]=b1q.x; e2v[5]=b1q.y; e2v[6]=b1q.z; e2v[7]=b1q.w;
        }

        int lo = max(j0 - R, 0), hi = min(j0 + R, WW - 1);
        float racc1 = 0.f, racc2 = 0.f;
        for (int jj = lo; jj <= hi; ++jj) { racc1 += r1[swz(jj)]; racc2 += r2[swz(jj)]; }
        float ov[8];
        #pragma unroll
        for (int d = 0; d < 8; ++d) {
            if (d > 0) {
                int add = j0 + d + R, sub = j0 + d - R - 1;
                if (add < WW) { racc1 += r1[swz(add)]; racc2 += r2[swz(add)]; }
                if (sub >= 0) { racc1 -= r1[swz(sub)]; racc2 -= r2[swz(sub)]; }
            }
            int j = j0 + d;
            float inv = 1.f / (float)(ch * (min(j + R, WW - 1) - max(j - R, 0) + 1));
            float v1 = racc1 * inv, v2 = racc2 * inv;
            float den = fabsf(v1 - v2) + 1e-4f;
            if (EPI == 1) {
                ov[d] = (fabsf(e1v[d]) - v2) / den;
            } else {
                ov[d] = ((e1v[d] - v2) / den + 0.01f) * e2v[d];
            }
        }
        float4* d4 = (float4*)&dst[rowbase];
        d4[0] = make_float4(ov[0], ov[1], ov[2], ov[3]);
        d4[1] = make_float4(ov[4], ov[5], ov[6], ov[7]);
    }
}

// ---------------- reduction ----------------
// Pairs element (hi,off): M[(hi<<23)+off] with M[(hi<<23)+off+(1<<22)]; n4 = n/4.
__global__ __launch_bounds__(256) void reduce1(const float* __restrict__ M,
                                               float* __restrict__ partials, int n4) {
    int tid = blockIdx.x * 256 + threadIdx.x;
    float v = 0.f;
    for (int q = tid; q < n4; q += 256 * 1024) {
        int i = q << 2;
        int hi = i >> 23, off = i & ((1 << 22) - 1);
        int hb = (i >> 22) & 1;                    // 64-stack: i in [0,2^23); 32-stack: hi=0
        (void)hb;
        int base = ((i >> 22) << 22);              // selects the correct 2^22-aligned a-block
        // a-block index: blocks 0,2 hold first operand; +1 block holds partner
        int ablk = (i >> 22) * 2 - ((i >> 22) & 0);  // not used; compute directly below
        (void)ablk; (void)base; (void)hi;
        int h = i >> 22;                           // 0..1 (32-stack) or 0..1 within each half
        // For layout [Rgx|Lgx|Rgy|Lgy]: operand a lives in block (h*2) remapped:
        int seg = i >> 22;                         // 0 -> gx pair, 1 -> gy pair (n=2^23)
        size_t ai = ((size_t)seg << 23) >> 1;      // seg*2^22*2 /2 ... compute plainly:
        ai = (size_t)seg * ((size_t)2 << 22);      // seg * 2^23
        ai = (ai >> 1);                            // WRONG path guard; recompute clean:
        size_t aidx = (size_t)seg * (1ull << 23) + (size_t)off;
        float4 a = *(const float4*)(M + aidx);
        float4 b = *(const float4*)(M + aidx + (1u << 22));
        v += a.x * expf(-10.f * (a.x + b.x));
        v += a.y * expf(-10.f * (a.y + b.y));
        v += a.z * expf(-10.f * (a.z + b.z));
        v += a.w * expf(-10.f * (a.w + b.w));
    }
    for (int off = 32; off; off >>= 1) v += __shfl_down(v, off);
    __shared__ float lds[4];
    int lane = threadIdx.x & 63, wv = threadIdx.x >> 6;
    if (lane == 0) lds[wv] = v;
    __syncthreads();
    if (threadIdx.x == 0) partials[blockIdx.x] = lds[0] + lds[1] + lds[2] + lds[3];
}

__global__ __launch_bounds__(256) void reduce2(const float* __restrict__ partials,
                                               float* __restrict__ out, float scale, int n) {
    float v = 0.f;
    for (int i = threadIdx.x; i < n; i += 256) v += partials[i];
    for (int off = 32; off; off >>= 1) v += __shfl_down(v, off);
    __shared__ float lds[4];
    int lane = threadIdx.x & 63, wv = threadIdx.x >> 6;
    if (lane == 0) lds[wv] = v;
    __syncthreads();
    if (threadIdx.x == 0) atomicAdd(out, (lds[0] + lds[1] + lds[2] + lds[3]) * scale);
}

// ---------------- host orchestration ----------------

// Pool pipeline over `planes` stacked planes. G holds g; map ends in A.
static void pool_pipeline(float* G, float* A, float* B, float* C, int planes, hipStream_t s) {
    int gp = planes * (HH / 16);
    dual_pool<true , 4, 16><<<gp, 256, 0, s>>>(G, A, B);                 // A=max9|g|, B=min9|g|
    davg_pool<8, 1, 16><<<gp, 256, 0, s>>>(A, B, G, nullptr, C);         // C=gn1
    avg_abs_pool<2, 16><<<gp, 256, 0, s>>>(G, A);                        // A=go
    dual_pool<false, 3, 16><<<gp, 256, 0, s>>>(A, B, G);                 // B=max7, G=min7
    davg_pool<3, 2, 16><<<gp, 256, 0, s>>>(B, G, A, C, A);               // A=map
}

extern "C" void kernel_launch(void* const* d_in, const int* in_sizes, int n_in,
                              void* d_out, int out_size, void* d_ws, size_t ws_size,
                              hipStream_t stream) {
    const float* Rrgb = (const float*)d_in[0];
    const float* Lrgb = (const float*)d_in[1];
    float* out = (float*)d_out;
    float* w = (float*)d_ws;
    const float scale = 1.f / (float)P16N;
    const int gradblk = (P16N / 4 + 255) / 256;

    hipMemsetAsync(out, 0, sizeof(float) * (size_t)out_size, stream);

    const size_t stack64 = (size_t)64 * SS;
    if (ws_size >= 4 * stack64 * sizeof(float)) {
        // 4 buffers of 64 planes: layout [0..16)=Rgx [16..32)=Lgx [32..48)=Rgy [48..64)=Lgy
        float* G = w;
        float* A = G + stack64;
        float* B = A + stack64;
        float* C = B + stack64;
        grad_both<<<gradblk, 256, 0, stream>>>(Rrgb, G, 0, 32, 2);
        grad_both<<<gradblk, 256, 0, stream>>>(Lrgb, G, 16, 48, 2);
        pool_pipeline(G, A, B, C, 64, stream);
        float* partials = C;                      // C dead after map
        reduce1<<<1024, 256, 0, stream>>>(A, partials, (2 * P16N) / 4);
        reduce2<<<1, 256, 0, stream>>>(partials, out, scale, 1024);
    } else {
        // fallback: 4 buffers of 32 planes (134 MB), one direction at a time
        const size_t stack32 = (size_t)32 * SS;
        float* G = w;
        float* A = G + stack32;
        float* B = A + stack32;
        float* C = B + stack32;
        for (int dir = 0; dir < 2; ++dir) {
            grad_both<<<gradblk, 256, 0, stream>>>(Rrgb, G, 0, 0, dir);
            grad_both<<<gradblk, 256, 0, stream>>>(Lrgb, G, 16, 16, dir);
            pool_pipeline(G, A, B, C, 32, stream);
            float* partials = C;
            reduce1<<<1024, 256, 0, stream>>>(A, partials, P16N / 4);
            reduce2<<<1, 256, 0, stream>>>(partials, out, scale, 1024);
        }
    }
}